// Round 3
// baseline (189.752 us; speedup 1.0000x reference)
//
#include <hip/hip_runtime.h>
#include <hip/hip_bf16.h>

// ---------------- problem constants ----------------
#define Bc   8
#define Cc   256
#define Hc   64
#define Wc   64
#define Mc   4
#define Rc   4
#define HWc  4096
#define KDIM 1024          // M*C
#define NROW 32768         // B*H*W

#define F_OUT_SIZE 8388608        // B*C*H*W
#define LOSS_IDX   8388608
#define OFFS_BASE  8388609        // offsets output base in d_out

// ---------------- ws layout (bytes) ----------------
#define FCT_OFF    0u              // f32 [B][H][W][C]     33,554,432
#define HEAD_OFF   33554432u       // bf16 [NROW][KDIM]    67,108,864  (also conv partials earlier in stream)
#define WBF_OFF    100663296u      // bf16 [C][KDIM]          524,288
#define ATTN_OFF   101187584u      // f32 [B][M][HW]          524,288
#define ALPHA_OFF  101711872u      // f32 [8]
#define LOSSP_OFF  101712128u      // f32 [512]
#define WREP_OFF   101714176u      // f32 [512][12][9]        221,184

typedef unsigned short u16;
typedef __attribute__((ext_vector_type(8))) short bf16x8;
typedef __attribute__((ext_vector_type(4))) float f32x4;

static __device__ __forceinline__ u16 f2bf(float f) {
    unsigned int u = __float_as_uint(f);
    unsigned int r = (u + 0x7FFFu + ((u >> 16) & 1u)) >> 16;
    return (u16)r;
}

// ---------------- kernel 1: transpose F_c -> [b][hw][c] fp32 ----------------
__global__ __launch_bounds__(256) void transpose_fc(const float* __restrict__ Fc,
                                                    float* __restrict__ Fct) {
    __shared__ float tile[32][33];
    int blk = blockIdx.x;
    int b   = blk >> 10;
    int rem = blk & 1023;
    int hw0 = (rem >> 3) << 5;
    int c0  = (rem & 7) << 5;
    int tid = threadIdx.x;
#pragma unroll
    for (int it = 0; it < 4; ++it) {
        int idx = it * 256 + tid;
        int ci = idx >> 5, hwi = idx & 31;
        tile[ci][hwi] = Fc[(((size_t)b << 8) + c0 + ci) * HWc + hw0 + hwi];
    }
    __syncthreads();
#pragma unroll
    for (int it = 0; it < 4; ++it) {
        int idx = it * 256 + tid;
        int hwi = idx >> 5, ci = idx & 31;
        Fct[(((size_t)b << 12) + hw0 + hwi) * Cc + c0 + ci] = tile[ci][hwi];
    }
}

// ---------------- kernel 2: cast w_fuse -> bf16 [co][k]  +  repack conv weights ----------------
// blocks 0..255: w_fuse cast; blocks 256..271: repack w_off/w_attn -> wrep[ch][12][9]
__global__ __launch_bounds__(256) void cast_wfuse(const float* __restrict__ wf,
                                                  u16* __restrict__ wbf,
                                                  const float* __restrict__ w_off,
                                                  const float* __restrict__ w_attn,
                                                  float* __restrict__ wrep) {
    const int tid = threadIdx.x;
    if (blockIdx.x < 256) {
        int i = blockIdx.x * 256 + tid;      // 65536 groups of 4
        float4 v = *(const float4*)(wf + (size_t)i * 4);
        ushort4 o;
        o.x = f2bf(v.x); o.y = f2bf(v.y); o.z = f2bf(v.z); o.w = f2bf(v.w);
        *(ushort4*)(wbf + (size_t)i * 4) = o;
    } else {
        const int idx0 = (blockIdx.x - 256) * 3456;
        for (int j = tid; j < 3456; j += 256) {
            const int idx = idx0 + j;                 // [0, 55296)
            const int ch = idx / 108;
            const int rem = idx - ch * 108;
            const int oc = rem / 9;
            const int k = rem - oc * 9;
            const float v = (oc < 8) ? w_off[((size_t)(oc * 512) + ch) * 9 + k]
                                     : w_attn[((size_t)((oc - 8) * 512) + ch) * 9 + k];
            wrep[idx] = v;
        }
    }
}

// ---------------- kernel 3: 3x3 conv v3 -> per-channel-group partials ----------------
// grid: (b*8+s, cg) = (64, 16); block 256. Thread owns 2 consecutive pixels in an 8-row slab.
// partials layout: [cg][b][oc(12)][4096] f32  (25.2 MB, lives in head region)
__global__ __launch_bounds__(256, 4) void conv_v3(
    const float* __restrict__ Fx, const float* __restrict__ Fc,
    const float* __restrict__ wrep, float* __restrict__ partials) {
    // lds col 0 = img col -1 (zero), 1..64 = img cols, 65 = img col 64 (zero); stride 73 (conflict-free)
    __shared__ float lds[2][10][73];

    const int tid = threadIdx.x;
    const int b = blockIdx.x >> 3, s = blockIdx.x & 7;
    const int cg = blockIdx.y;
    const int rq = tid >> 5;             // row in slab [0,8)
    const int c  = (tid & 31) << 1;      // pixel col base {0,2,...,62}

    if (tid < 20) {                      // zero halo cols, both buffers
        lds[tid / 10][tid % 10][0]  = 0.f;
        lds[tid / 10][tid % 10][65] = 0.f;
    }

    float acc[12][2] = {};

    // staging assignment: 160 float4 slots (10 rows x 16 col-groups)
    const int r0 = tid >> 4, cw = (tid & 15) << 2;
    const int grow = (s << 3) - 1 + r0;
    const bool ldr = (tid < 160) && (grow >= 0) && (grow < 64);

    auto plane_for = [&](int chi) -> const float* {
        const int ch = cg * 32 + chi;
        return (ch < 256) ? Fx + (((size_t)b << 8) + ch) * HWc
                          : Fc + (((size_t)b << 8) + (ch - 256)) * HWc;
    };

    const float4 fz = {0.f, 0.f, 0.f, 0.f};
    float4 v = ldr ? *(const float4*)(plane_for(0) + grow * 64 + cw) : fz;
    if (tid < 160) {
        lds[0][r0][1 + cw]     = v.x;
        lds[0][r0][1 + cw + 1] = v.y;
        lds[0][r0][1 + cw + 2] = v.z;
        lds[0][r0][1 + cw + 3] = v.w;
    }

    int cur = 0;
    for (int chi = 0; chi < 32; ++chi) {
        if (chi < 31)
            v = ldr ? *(const float4*)(plane_for(chi + 1) + grow * 64 + cw) : fz;
        __syncthreads();

        float a[3][4];
#pragma unroll
        for (int dy = 0; dy < 3; ++dy)
#pragma unroll
            for (int k = 0; k < 4; ++k)
                a[dy][k] = lds[cur][rq + dy][c + k];

        const float* __restrict__ wp = wrep + (size_t)(cg * 32 + chi) * 108;
#pragma unroll
        for (int oc = 0; oc < 12; ++oc) {
#pragma unroll
            for (int t9 = 0; t9 < 9; ++t9) {
                const float w = wp[oc * 9 + t9];
                const int dy = t9 / 3, dx = t9 % 3;
                acc[oc][0] = fmaf(w, a[dy][dx],     acc[oc][0]);
                acc[oc][1] = fmaf(w, a[dy][dx + 1], acc[oc][1]);
            }
        }

        if (chi < 31 && tid < 160) {
            lds[cur ^ 1][r0][1 + cw]     = v.x;
            lds[cur ^ 1][r0][1 + cw + 1] = v.y;
            lds[cur ^ 1][r0][1 + cw + 2] = v.z;
            lds[cur ^ 1][r0][1 + cw + 3] = v.w;
        }
        cur ^= 1;
    }

    const size_t pbase = (((size_t)cg * 8 + b) * 12) * HWc + ((s << 3) + rq) * 64 + c;
#pragma unroll
    for (int oc = 0; oc < 12; ++oc) {
        float2 o; o.x = acc[oc][0]; o.y = acc[oc][1];
        *(float2*)(partials + pbase + (size_t)oc * HWc) = o;
    }
}

// ---------------- kernel 3b: reduce partials -> offsets/attn + loss partials ----------------
__global__ __launch_bounds__(256) void conv_reduce(
    const float* __restrict__ partials, const float* __restrict__ b_off,
    const float* __restrict__ b_attn, float* __restrict__ dout,
    float* __restrict__ attnb, float* __restrict__ lossp) {
    __shared__ float wr4[4];
    const int tid = threadIdx.x;
    const int i = blockIdx.x * 256 + tid;            // [0, 98304)
    const int boc = i >> 10;                         // uniform per block
    const int b = boc / 12, oc = boc % 12;
    const int pg = (i & 1023) << 2;

    float4 s = {0.f, 0.f, 0.f, 0.f};
#pragma unroll
    for (int cg = 0; cg < 16; ++cg) {
        const float4 v = *(const float4*)(partials + ((((size_t)cg * 8 + b) * 12 + oc) << 12) + pg);
        s.x += v.x; s.y += v.y; s.z += v.z; s.w += v.w;
    }

    float labs = 0.f;
    if (oc < 8) {
        const float bo = b_off[oc];
        s.x += bo; s.y += bo; s.z += bo; s.w += bo;
        *(float4*)(dout + OFFS_BASE + (((size_t)b * 8 + oc) << 12) + pg) = s;
        labs = fabsf(s.x) + fabsf(s.y) + fabsf(s.z) + fabsf(s.w);
    } else {
        const float ba = b_attn[oc - 8];
        float4 o;
        o.x = 1.f / (1.f + expf(-(s.x + ba)));
        o.y = 1.f / (1.f + expf(-(s.y + ba)));
        o.z = 1.f / (1.f + expf(-(s.z + ba)));
        o.w = 1.f / (1.f + expf(-(s.w + ba)));
        *(float4*)(attnb + (((size_t)b * 4 + (oc - 8)) << 12) + pg) = o;
    }
#pragma unroll
    for (int off = 32; off; off >>= 1) labs += __shfl_down(labs, off);
    if ((tid & 63) == 0) wr4[tid >> 6] = labs;
    __syncthreads();
    if (tid == 0) lossp[blockIdx.x] = wr4[0] + wr4[1] + wr4[2] + wr4[3];
}

// ---------------- kernel 4: loss reduce + alpha MLP ----------------
__global__ __launch_bounds__(256) void finalize_small(
    const float* __restrict__ lossp, const float* __restrict__ t,
    const float* __restrict__ w1, const float* __restrict__ b1,
    const float* __restrict__ w2, const float* __restrict__ b2,
    float* __restrict__ dout, float* __restrict__ alpha) {
    __shared__ float sd[4];
    const int tid = threadIdx.x;
    float s = 0.f;
    for (int i = tid; i < 384; i += 256) s += lossp[i];
#pragma unroll
    for (int off = 32; off; off >>= 1) s += __shfl_down(s, off);
    if ((tid & 63) == 0) sd[tid >> 6] = s;
    __syncthreads();
    if (tid == 0) dout[LOSS_IDX] = (sd[0] + sd[1] + sd[2] + sd[3]) * (1.f / 262144.f);

    for (int b = 0; b < 8; ++b) {
        __syncthreads();
        float v = 0.f;
        if (tid < 128) v = fmaxf(fmaf(t[b], w1[tid], b1[tid]), 0.f) * w2[tid];
#pragma unroll
        for (int off = 32; off; off >>= 1) v += __shfl_down(v, off);
        if ((tid & 63) == 0) sd[tid >> 6] = v;
        __syncthreads();
        if (tid == 0) alpha[b] = 1.f / (1.f + expf(-(sd[0] + sd[1] + b2[0])));
    }
}

// ---------------- kernel 5: bilinear gather -> head (bf16) ----------------
__global__ __launch_bounds__(256) void sample_head(
    const float* __restrict__ Fct, const float* __restrict__ dout,
    const float* __restrict__ attnb, const float* __restrict__ Wp,
    u16* __restrict__ head) {
    const int tid = threadIdx.x;
    const int wv = tid >> 6, lane = tid & 63;
    const int item = blockIdx.x * 4 + wv;           // (b, m, p)
    const int b = item >> 14;
    const int m = (item >> 12) & 3;
    const int p = item & 4095;
    const int h = p >> 6, wc = p & 63;

    const float off0 = dout[OFFS_BASE + (((size_t)b * 8 + 2 * m) << 12) + p];
    const float off1 = dout[OFFS_BASE + (((size_t)b * 8 + 2 * m + 1) << 12) + p];
    const float a    = attnb[(((size_t)b * 4 + m) << 12) + p];

    const float ysh = -1.f + h * (2.f / 63.f);
    const float xsw = -1.f + wc * (2.f / 63.f);

    const float* base = Fct + (((size_t)b << 12) * Cc);
    float ax = 0.f, ay = 0.f, az = 0.f, aw = 0.f;

#pragma unroll
    for (int r = 0; r < 4; ++r) {
        const float bpy = (r < 2) ? -0.5f : 0.5f;
        const float bpx = (r & 1) ? 0.5f : -0.5f;
        const float c0 = ysh + bpy + off0;   // used as gx (reference quirk)
        const float c1 = xsw + bpx + off1;   // used as gy
        const float ix = (c0 + 1.f) * 31.5f;
        const float iy = (c1 + 1.f) * 31.5f;
        const float x0 = floorf(ix), y0 = floorf(iy);
        const float wx1 = ix - x0, wx0 = 1.f - wx1;
        const float wy1 = iy - y0, wy0 = 1.f - wy1;
        const float wr = Wp[m * 4 + r];
#pragma unroll
        for (int c4 = 0; c4 < 4; ++c4) {
            const int dy = c4 >> 1, dx = c4 & 1;
            const float yf = y0 + dy, xf = x0 + dx;
            if (yf >= 0.f && yf < 64.f && xf >= 0.f && xf < 64.f) {
                const int yi = (int)yf, xi = (int)xf;
                const float w = wr * (dy ? wy1 : wy0) * (dx ? wx1 : wx0);
                const float4 v = *(const float4*)(base + ((size_t)((yi << 6) + xi)) * Cc + (lane << 2));
                ax = fmaf(w, v.x, ax); ay = fmaf(w, v.y, ay);
                az = fmaf(w, v.z, az); aw = fmaf(w, v.w, aw);
            }
        }
    }
    const size_t row = ((size_t)b << 12) + p;
    ushort4 o;
    o.x = f2bf(a * ax); o.y = f2bf(a * ay); o.z = f2bf(a * az); o.w = f2bf(a * aw);
    *(ushort4*)(head + row * KDIM + (m << 8) + (lane << 2)) = o;
}

// ---------------- kernel 6: fuse GEMM (bf16 MFMA, global_load_lds) + blend epilogue ----------------
// LDS layout per matrix: 4 k-quarters, each [128 rows][16B], quarter stride 1040 u16 (2080B)
// -> DMA-contiguous per wave-instr AND 2-way-free on ds_read_b128 fragment reads.
#define QSTR 1040
__global__ __launch_bounds__(256) void fuse_gemm(
    const u16* __restrict__ head, const u16* __restrict__ wbf,
    const float* __restrict__ Fx, const float* __restrict__ bfuse,
    const float* __restrict__ alpha, float* __restrict__ dout) {
    __shared__ __attribute__((aligned(16))) u16 Asl[4 * QSTR];
    __shared__ __attribute__((aligned(16))) u16 Bsl[4 * QSTR];

    const int tid = threadIdx.x;
    const int lane = tid & 63, wv = tid >> 6;
    const int wm = wv >> 1, wn = wv & 1;
    const int l15 = lane & 15, g = lane >> 4;
    const size_t arow0 = (size_t)blockIdx.y * 128;
    const int co0 = blockIdx.x * 128;

    f32x4 acc[4][4] = {};

    // staging: wave 0,1 -> A halves; wave 2,3 -> B halves
    const int half = wv & 1;
    const u16* gsrc = (wv < 2) ? head + (arow0 + half * 64 + lane) * KDIM
                               : wbf + ((size_t)co0 + half * 64 + lane) * KDIM;
    u16* lbase_ = (wv < 2) ? Asl : Bsl;
    u16* lds_w = lbase_ + half * 512;   // + g*QSTR per quarter; lane offset handled by HW

    for (int kt = 0; kt < 32; ++kt) {
        __syncthreads();   // previous compute done; LDS free
        const int kb = kt * 32;
#pragma unroll
        for (int q = 0; q < 4; ++q) {
            __builtin_amdgcn_global_load_lds(
                (const __attribute__((address_space(1))) unsigned int*)(gsrc + kb + q * 8),
                (__attribute__((address_space(3))) unsigned int*)(lds_w + q * QSTR),
                16, 0, 0);
        }
        __syncthreads();   // vmcnt(0) drained by compiler before barrier

        bf16x8 af[4], bf[4];
#pragma unroll
        for (int f = 0; f < 4; ++f) {
            af[f] = *(const bf16x8*)&Asl[g * QSTR + (wm * 64 + f * 16 + l15) * 8];
            bf[f] = *(const bf16x8*)&Bsl[g * QSTR + (wn * 64 + f * 16 + l15) * 8];
        }
#pragma unroll
        for (int i = 0; i < 4; ++i)
#pragma unroll
            for (int j = 0; j < 4; ++j)
                acc[i][j] = __builtin_amdgcn_mfma_f32_16x16x32_bf16(af[i], bf[j], acc[i][j], 0, 0, 0);
    }

    const int b = (int)(arow0 >> 12);
    const float al = alpha[b], il = 1.f - al;
    const int pixbase = (int)(arow0 & 4095);
#pragma unroll
    for (int i = 0; i < 4; ++i) {
        const int rowl = wm * 64 + i * 16 + g * 4;
        const int pix = pixbase + rowl;
#pragma unroll
        for (int j = 0; j < 4; ++j) {
            const int co = co0 + wn * 64 + j * 16 + l15;
            const float bias = bfuse[co];
            const size_t idx = (((size_t)b << 8) + co) * HWc + pix;
            const float4 fx = *(const float4*)(Fx + idx);
            const f32x4 vv = acc[i][j];
            float4 o;
            o.x = al * (vv[0] + bias) + il * fx.x;
            o.y = al * (vv[1] + bias) + il * fx.y;
            o.z = al * (vv[2] + bias) + il * fx.z;
            o.w = al * (vv[3] + bias) + il * fx.w;
            *(float4*)(dout + idx) = o;
        }
    }
}

// ---------------- launcher ----------------
extern "C" void kernel_launch(void* const* d_in, const int* in_sizes, int n_in,
                              void* d_out, int out_size, void* d_ws, size_t ws_size,
                              hipStream_t stream) {
    const float* F_x    = (const float*)d_in[0];
    const float* F_c    = (const float*)d_in[1];
    const float* t      = (const float*)d_in[2];
    const float* w_off  = (const float*)d_in[3];
    const float* b_off  = (const float*)d_in[4];
    const float* w_attn = (const float*)d_in[5];
    const float* b_attn = (const float*)d_in[6];
    const float* Wp     = (const float*)d_in[7];
    const float* w_fuse = (const float*)d_in[8];
    const float* b_fuse = (const float*)d_in[9];
    const float* w1     = (const float*)d_in[10];
    const float* b1     = (const float*)d_in[11];
    const float* w2     = (const float*)d_in[12];
    const float* b2     = (const float*)d_in[13];
    float* out = (float*)d_out;

    char* ws = (char*)d_ws;
    float* Fct   = (float*)(ws + FCT_OFF);
    u16*   head  = (u16*)(ws + HEAD_OFF);
    float* parts = (float*)(ws + HEAD_OFF);   // reuse head region for conv partials
    u16*   wbf   = (u16*)(ws + WBF_OFF);
    float* attnb = (float*)(ws + ATTN_OFF);
    float* alphb = (float*)(ws + ALPHA_OFF);
    float* lossp = (float*)(ws + LOSSP_OFF);
    float* wrep  = (float*)(ws + WREP_OFF);

    transpose_fc<<<dim3(8192), dim3(256), 0, stream>>>(F_c, Fct);
    cast_wfuse<<<dim3(272), dim3(256), 0, stream>>>(w_fuse, wbf, w_off, w_attn, wrep);
    conv_v3<<<dim3(64, 16), dim3(256), 0, stream>>>(F_x, F_c, wrep, parts);
    conv_reduce<<<dim3(384), dim3(256), 0, stream>>>(parts, b_off, b_attn, out, attnb, lossp);
    finalize_small<<<dim3(1), dim3(256), 0, stream>>>(lossp, t, w1, b1, w2, b2, out, alphb);
    sample_head<<<dim3(32768), dim3(256), 0, stream>>>(Fct, out, attnb, Wp, head);
    fuse_gemm<<<dim3(2, 256), dim3(256), 0, stream>>>(head, wbf, F_x, b_fuse, alphb, out);
}

// Round 5
// 139.956 us; speedup vs baseline: 1.3558x; 1.3558x over previous
//
#include <hip/hip_runtime.h>
#include <hip/hip_bf16.h>

// ---------------- problem constants ----------------
#define Bc   8
#define Cc   256
#define Hc   64
#define Wc   64
#define HWc  4096
#define KDIM 1024          // M*C

#define LOSS_IDX   8388608
#define OFFS_BASE  8388609        // offsets output base in d_out

// ---------------- ws layout (bytes) ----------------
#define XT_OFF     0u              // bf16 [B][HW][512] hi   33,554,432
#define HEAD_OFF   33554432u       // bf16 [NROW][KDIM] 64MB; first 33.5MB doubles as Xlo (consumed by conv before sample_head writes head)
#define WBF_OFF    100663296u      // bf16 [C][KDIM]          524,288
#define ATTN_OFF   101187584u      // f32 [B][M][HW]          524,288
#define ALPHA_OFF  101711872u      // f32 [8]
#define LOSSP_OFF  101712128u      // f32 [256]
#define WREP_OFF   101714176u      // wconv blob              221,184 (8 steps x 1728 granules x 16B)
#define ZPAGE_OFF  101935360u      // 256 B zeros

typedef unsigned short u16;
typedef __attribute__((ext_vector_type(8))) short bf16x8;
typedef __attribute__((ext_vector_type(8))) unsigned short u16x8;
typedef __attribute__((ext_vector_type(4))) float f32x4;

static __device__ __forceinline__ u16 f2bf(float f) {
    unsigned int u = __float_as_uint(f);
    unsigned int r = (u + 0x7FFFu + ((u >> 16) & 1u)) >> 16;
    return (u16)r;
}
static __device__ __forceinline__ float bf2f(u16 h) {
    return __uint_as_float(((unsigned int)h) << 16);
}

// ---------------- kernel 1: pack X -> channel-last bf16 hi/lo ----------------
// Xt/Xlo: [b][hw][512] with ch 0..255 = F_x, 256..511 = F_c
__global__ __launch_bounds__(256) void pack_x(const float* __restrict__ Fx,
                                              const float* __restrict__ Fc,
                                              u16* __restrict__ Xt, u16* __restrict__ Xlo) {
    __shared__ float tile[32][33];
    const int blk = blockIdx.x;               // 16384
    const int b = blk >> 11;
    const int rem = blk & 2047;
    const int hw0 = (rem >> 4) << 5;
    const int c0 = (rem & 15) << 5;           // 0..480
    const int tid = threadIdx.x;
    const int ci = tid >> 5, hwi = tid & 31;
#pragma unroll
    for (int it = 0; it < 4; ++it) {
        const int cc = c0 + ci + it * 8;
        const float* src = (cc < 256) ? Fx + (((size_t)b << 8) + cc) * HWc
                                      : Fc + (((size_t)b << 8) + cc - 256) * HWc;
        tile[ci + it * 8][hwi] = src[hw0 + hwi];
    }
    __syncthreads();
    const int pix = tid >> 3, c4 = (tid & 7) << 2;
    const size_t obase = (((size_t)b << 12) + hw0 + pix) * 512 + c0 + c4;
    ushort4 hi4, lo4;
#pragma unroll
    for (int k = 0; k < 4; ++k) {
        const float v = tile[c4 + k][pix];
        const u16 h = f2bf(v);
        ((u16*)&hi4)[k] = h;
        ((u16*)&lo4)[k] = f2bf(v - bf2f(h));
    }
    *(ushort4*)(Xt + obase) = hi4;
    *(ushort4*)(Xlo + obase) = lo4;
}

// ---------------- kernel 2: prep — wfuse cast + wconv swizzled blob + zpage ----------------
// wconv blob granule order (16B granules): [step8][sub2][prec2][tap9][pair6][slot4][par2]
// content: oc = pair*2+par; ch-chunk c = slot ^ (pair&3); ch = step*64 + sub*32 + c*8 + j
__global__ __launch_bounds__(256) void prep(const float* __restrict__ wf,
                                            u16* __restrict__ wbf,
                                            const float* __restrict__ w_off,
                                            const float* __restrict__ w_attn,
                                            u16* __restrict__ wconv,
                                            float* __restrict__ zpage) {
    const int tid = threadIdx.x;
    if (blockIdx.x < 256) {
        const int i = blockIdx.x * 256 + tid;
        const float4 v = *(const float4*)(wf + (size_t)i * 4);
        ushort4 o;
        o.x = f2bf(v.x); o.y = f2bf(v.y); o.z = f2bf(v.z); o.w = f2bf(v.w);
        *(ushort4*)(wbf + (size_t)i * 4) = o;
    } else if (blockIdx.x < 264) {            // EXACTLY 8 steps (round-4 bug: was 16 -> clobbered zpage)
        const int step = blockIdx.x - 256;
        for (int n = tid; n < 1728; n += 256) {
            const int par = n & 1;
            const int slot = (n >> 1) & 3;
            const int pair = (n >> 3) % 6;
            const int tap = (n / 48) % 9;
            const int prec = (n / 432) & 1;
            const int sub = n / 864;
            const int oc = pair * 2 + par;
            const int c = slot ^ (pair & 3);
            const int ch = step * 64 + sub * 32 + c * 8;
            u16x8 out;
#pragma unroll
            for (int j = 0; j < 8; ++j) {
                const float v = (oc < 8)
                    ? w_off[((size_t)oc * 512 + ch + j) * 9 + tap]
                    : w_attn[((size_t)(oc - 8) * 512 + ch + j) * 9 + tap];
                const u16 h = f2bf(v);
                out[j] = prec ? f2bf(v - bf2f(h)) : h;
            }
            *(u16x8*)(wconv + ((size_t)step * 1728 + n) * 8) = out;
        }
    } else {
        if (tid < 64) zpage[tid] = 0.f;
    }
}

// ---------------- kernel 3: conv as split-bf16 MFMA implicit GEMM ----------------
// 256 blocks (b*32 + rowpair), 512 threads = 8 waves (2 K-groups x 4 pixel-quarters).
// LDS: X [buf2][prec2][row4][pos66][chunk8] 16B granules (buf 67584, prec 33792, row 8448)
//      B at 135168: [sub2][prec2][tap9][pair6][slot4][par2] granules. total 162816
#define XBUF_STR 67584
#define XPRC_STR 33792
#define XROW_STR 8448
#define B_BASE   135168
__global__ __launch_bounds__(512) void conv_mfma(
    const u16* __restrict__ Xt, const u16* __restrict__ Xlo,
    const u16* __restrict__ wconv, const float* __restrict__ zpage,
    const float* __restrict__ b_off, const float* __restrict__ b_attn,
    float* __restrict__ dout, float* __restrict__ attnb, float* __restrict__ lossp) {
    __shared__ char smem[163840];

    const int tid = threadIdx.x;
    const int wv = tid >> 6, lane = tid & 63;
    const int gp = wv >> 2, qd = wv & 3;
    const int l15 = lane & 15, g = lane >> 4;
    const int b = blockIdx.x >> 5;
    const int h0 = (blockIdx.x & 31) * 2;
    const int wrow = qd >> 1, wcol0 = (qd & 1) * 32;

    // zero halo granules (pos 0 and 65 of every row/prec/buf)
    if (tid < 256) {
        const int bu = tid >> 7, pr = (tid >> 6) & 1, rr = (tid >> 4) & 3;
        const int hp = (tid >> 3) & 1, cc = tid & 7;
        const int p = hp ? 65 : 0;
        const float4 z = {0.f, 0.f, 0.f, 0.f};
        *(float4*)(smem + bu * XBUF_STR + pr * XPRC_STR + rr * XROW_STR + p * 128 + cc * 16) = z;
    }

    // per-lane read offsets: A-frag (f, dx) -> byte offset (buf folded in by toggling)
    int pre[2][3];
#pragma unroll
    for (int f = 0; f < 2; ++f)
#pragma unroll
        for (int dx = 0; dx < 3; ++dx) {
            const int p = wcol0 + f * 16 + l15 + dx;      // 0..65
            pre[f][dx] = wrow * XROW_STR + p * 128 + ((((gp << 2) | g) ^ (p & 7)) << 4);
        }
    const int bpair = l15 >> 1, bpar = l15 & 1;
    const int vb = B_BASE + gp * 13824 + bpair * 128 + ((g ^ (bpair & 3)) << 5) + bpar * 16;

    auto stage_X = [&](int step, int buf) {
#pragma unroll
        for (int k = 0; k < 9; ++k) {
            const int f = wv * 9 + k;                     // 0..71
            const int prec = f / 36, rr = (f / 9) & 3, i = f % 9;
            const int p = i * 8 + (lane >> 3);
            const int c = (lane & 7) ^ (p & 7);
            const int col = p - 1;
            const int h = h0 - 1 + rr;
            const bool act = (p >= 1) && (p <= 64);
            const u16* srcb = prec ? Xlo : Xt;
            const char* gsrc = (h >= 0 && h < 64)
                ? (const char*)(srcb + (((size_t)((b << 12) + h * 64 + col)) << 9) + step * 64 + c * 8)
                : (const char*)zpage + ((lane & 7) << 4);
            char* ldst = smem + buf * XBUF_STR + prec * XPRC_STR + rr * XROW_STR + i * 1024;
            if (act)
                __builtin_amdgcn_global_load_lds(
                    (const __attribute__((address_space(1))) unsigned int*)gsrc,
                    (__attribute__((address_space(3))) unsigned int*)ldst, 16, 0, 0);
        }
    };
    auto stage_B = [&](int step) {
        for (int i = wv; i < 27; i += 8) {
            const char* gsrc = (const char*)wconv + (((size_t)step * 1728) + i * 64 + lane) * 16;
            char* ldst = smem + B_BASE + i * 1024;
            __builtin_amdgcn_global_load_lds(
                (const __attribute__((address_space(1))) unsigned int*)gsrc,
                (__attribute__((address_space(3))) unsigned int*)ldst, 16, 0, 0);
        }
    };

    __syncthreads();                 // halo zeros visible
    stage_X(0, 0);
    stage_B(0);
    __syncthreads();                 // full drain: X0 + B0 ready

    f32x4 acc0 = {}, acc1 = {};

    for (int step = 0; step < 8; ++step) {
        if (step < 7) {
            stage_X(step + 1, (step + 1) & 1);
            asm volatile("s_waitcnt vmcnt(9)" ::: "memory");
        } else {
            asm volatile("s_waitcnt vmcnt(0)" ::: "memory");
        }
        __builtin_amdgcn_s_barrier();
        __builtin_amdgcn_sched_barrier(0);

#pragma unroll
        for (int tap = 0; tap < 9; ++tap) {
            const int dy = tap / 3, dx = tap % 3;
            const bf16x8 bh = *(const bf16x8*)(smem + vb + tap * 768);
            const bf16x8 bl = *(const bf16x8*)(smem + vb + 6912 + tap * 768);
            const bf16x8 a0h = *(const bf16x8*)(smem + pre[0][dx] + dy * XROW_STR);
            const bf16x8 a1h = *(const bf16x8*)(smem + pre[1][dx] + dy * XROW_STR);
            const bf16x8 a0l = *(const bf16x8*)(smem + pre[0][dx] + XPRC_STR + dy * XROW_STR);
            const bf16x8 a1l = *(const bf16x8*)(smem + pre[1][dx] + XPRC_STR + dy * XROW_STR);
            acc0 = __builtin_amdgcn_mfma_f32_16x16x32_bf16(a0h, bh, acc0, 0, 0, 0);
            acc1 = __builtin_amdgcn_mfma_f32_16x16x32_bf16(a1h, bh, acc1, 0, 0, 0);
            acc0 = __builtin_amdgcn_mfma_f32_16x16x32_bf16(a0h, bl, acc0, 0, 0, 0);
            acc1 = __builtin_amdgcn_mfma_f32_16x16x32_bf16(a1h, bl, acc1, 0, 0, 0);
            acc0 = __builtin_amdgcn_mfma_f32_16x16x32_bf16(a0l, bh, acc0, 0, 0, 0);
            acc1 = __builtin_amdgcn_mfma_f32_16x16x32_bf16(a1l, bh, acc1, 0, 0, 0);
        }

        __builtin_amdgcn_sched_barrier(0);
        __builtin_amdgcn_s_barrier();
        __builtin_amdgcn_sched_barrier(0);   // keep stage_B below the barrier
        if (step < 7) stage_B(step + 1);
        const int d = (step & 1) ? -XBUF_STR : XBUF_STR;
#pragma unroll
        for (int f = 0; f < 2; ++f)
#pragma unroll
            for (int dx = 0; dx < 3; ++dx) pre[f][dx] += d;
    }

    // ---- epilogue: combine K-groups, add bias, write offsets/attn, loss partial ----
    __syncthreads();
    float* eL = (float*)smem;        // [2 groups][12 oc][128 pix] f32 = 12 KB
    if (l15 < 12) {
#pragma unroll
        for (int r = 0; r < 4; ++r) {
            const int px0 = wrow * 64 + wcol0 + g * 4 + r;
            eL[(gp * 12 + l15) * 128 + px0] = acc0[r];
            eL[(gp * 12 + l15) * 128 + px0 + 16] = acc1[r];
        }
    }
    __syncthreads();
    float labs = 0.f;
    if (tid < 256) {
        const int oc = tid >> 5, seg = tid & 31;
        const float4 v0 = *(const float4*)&eL[oc * 128 + seg * 4];
        const float4 v1 = *(const float4*)&eL[(12 + oc) * 128 + seg * 4];
        const float bo = b_off[oc];
        float4 o;
        o.x = v0.x + v1.x + bo; o.y = v0.y + v1.y + bo;
        o.z = v0.z + v1.z + bo; o.w = v0.w + v1.w + bo;
        *(float4*)(dout + OFFS_BASE + (((size_t)b * 8 + oc) << 12) + h0 * 64 + seg * 4) = o;
        labs = fabsf(o.x) + fabsf(o.y) + fabsf(o.z) + fabsf(o.w);
    } else if (tid < 384) {
        const int t2 = tid - 256;
        const int oc = t2 >> 5, seg = t2 & 31;
        const float4 v0 = *(const float4*)&eL[(8 + oc) * 128 + seg * 4];
        const float4 v1 = *(const float4*)&eL[(20 + oc) * 128 + seg * 4];
        const float ba = b_attn[oc];
        float4 o;
        o.x = 1.f / (1.f + expf(-(v0.x + v1.x + ba)));
        o.y = 1.f / (1.f + expf(-(v0.y + v1.y + ba)));
        o.z = 1.f / (1.f + expf(-(v0.z + v1.z + ba)));
        o.w = 1.f / (1.f + expf(-(v0.w + v1.w + ba)));
        *(float4*)(attnb + (((size_t)b * 4 + oc) << 12) + h0 * 64 + seg * 4) = o;
    }
#pragma unroll
    for (int off = 32; off; off >>= 1) labs += __shfl_down(labs, off);
    float* wr = (float*)(smem + 14336);
    if (lane == 0) wr[wv] = labs;
    __syncthreads();
    if (tid == 0) {
        float s = 0.f;
#pragma unroll
        for (int i = 0; i < 8; ++i) s += wr[i];
        lossp[blockIdx.x] = s;
    }
}

// ---------------- kernel 4: loss reduce + alpha MLP ----------------
__global__ __launch_bounds__(256) void finalize_small(
    const float* __restrict__ lossp, const float* __restrict__ t,
    const float* __restrict__ w1, const float* __restrict__ b1,
    const float* __restrict__ w2, const float* __restrict__ b2,
    float* __restrict__ dout, float* __restrict__ alpha) {
    __shared__ float sd[4];
    const int tid = threadIdx.x;
    float s = lossp[tid];
#pragma unroll
    for (int off = 32; off; off >>= 1) s += __shfl_down(s, off);
    if ((tid & 63) == 0) sd[tid >> 6] = s;
    __syncthreads();
    if (tid == 0) dout[LOSS_IDX] = (sd[0] + sd[1] + sd[2] + sd[3]) * (1.f / 262144.f);

    for (int b = 0; b < 8; ++b) {
        __syncthreads();
        float v = 0.f;
        if (tid < 128) v = fmaxf(fmaf(t[b], w1[tid], b1[tid]), 0.f) * w2[tid];
#pragma unroll
        for (int off = 32; off; off >>= 1) v += __shfl_down(v, off);
        if ((tid & 63) == 0) sd[tid >> 6] = v;
        __syncthreads();
        if (tid == 0) alpha[b] = 1.f / (1.f + expf(-(sd[0] + sd[1] + b2[0])));
    }
}

// ---------------- kernel 5: bilinear gather (bf16) -> head ----------------
__global__ __launch_bounds__(256) void sample_head(
    const u16* __restrict__ Xt, const float* __restrict__ dout,
    const float* __restrict__ attnb, const float* __restrict__ Wp,
    u16* __restrict__ head) {
    const int tid = threadIdx.x;
    const int wv = tid >> 6, lane = tid & 63;
    const int item = blockIdx.x * 4 + wv;           // (b, m, p)
    const int b = item >> 14;
    const int m = (item >> 12) & 3;
    const int p = item & 4095;
    const int h = p >> 6, wc = p & 63;
    const int hl = lane >> 5, l32 = lane & 31;

    const float off0 = dout[OFFS_BASE + (((size_t)b * 8 + 2 * m) << 12) + p];
    const float off1 = dout[OFFS_BASE + (((size_t)b * 8 + 2 * m + 1) << 12) + p];
    const float a    = attnb[(((size_t)b * 4 + m) << 12) + p];

    const float ysh = -1.f + h * (2.f / 63.f);
    const float xsw = -1.f + wc * (2.f / 63.f);

    const u16* base = Xt + (((size_t)b << 12)) * 512 + 256 + l32 * 8;
    float acc[8] = {};

#pragma unroll
    for (int r = 0; r < 4; ++r) {
        const float bpy = (r < 2) ? -0.5f : 0.5f;
        const float bpx = (r & 1) ? 0.5f : -0.5f;
        const float c0 = ysh + bpy + off0;   // used as gx (reference quirk)
        const float c1 = xsw + bpx + off1;   // used as gy
        const float ix = (c0 + 1.f) * 31.5f;
        const float iy = (c1 + 1.f) * 31.5f;
        const float x0 = floorf(ix), y0 = floorf(iy);
        const float wx1 = ix - x0, wx0 = 1.f - wx1;
        const float wy1 = iy - y0, wy0 = 1.f - wy1;
        const float wr = Wp[m * 4 + r];
        const float xf = x0 + hl;            // this half-wave's x corner
        const float wxl = (hl ? wx1 : wx0) * wr;
#pragma unroll
        for (int cc = 0; cc < 2; ++cc) {
            const float yf = y0 + cc;
            if (yf >= 0.f && yf < 64.f && xf >= 0.f && xf < 64.f) {
                const int idx = (((int)yf) << 6) + (int)xf;
                const u16x8 v = *(const u16x8*)(base + (size_t)idx * 512);
                const float w = wxl * (cc ? wy1 : wy0);
#pragma unroll
                for (int j = 0; j < 8; ++j)
                    acc[j] = fmaf(w, bf2f(v[j]), acc[j]);
            }
        }
    }
#pragma unroll
    for (int j = 0; j < 8; ++j) acc[j] += __shfl_xor(acc[j], 32);
    if (lane < 32) {
        u16x8 o;
#pragma unroll
        for (int j = 0; j < 8; ++j) o[j] = f2bf(a * acc[j]);
        *(u16x8*)(head + (((size_t)b << 12) + p) * KDIM + m * 256 + l32 * 8) = o;
    }
}

// ---------------- kernel 6: fuse GEMM (bf16 MFMA) + blend epilogue (round-1 proven) ----------------
__global__ __launch_bounds__(256) void fuse_gemm(
    const u16* __restrict__ head, const u16* __restrict__ wbf,
    const float* __restrict__ Fx, const float* __restrict__ bfuse,
    const float* __restrict__ alpha, float* __restrict__ dout) {
    __shared__ u16 Asl[128 * 32];   // [row(pix)][k]
    __shared__ u16 Bsl[128 * 32];   // [col(co)][k]

    const int tid = threadIdx.x;
    const int lane = tid & 63, wv = tid >> 6;
    const int wm = wv >> 1, wn = wv & 1;
    const int l15 = lane & 15, g = lane >> 4;
    const size_t arow0 = (size_t)blockIdx.x * 128;
    const int co0 = blockIdx.y * 128;

    f32x4 acc[4][4] = {};

    const int row0 = tid >> 2, kc0 = (tid & 3) * 8;
    const int row1 = (tid + 256) >> 2, kc1 = ((tid + 256) & 3) * 8;

    for (int kt = 0; kt < 32; ++kt) {
        const int k0 = kt * 32;
        uint4 a0 = *(const uint4*)(head + (arow0 + row0) * KDIM + k0 + kc0);
        uint4 b0 = *(const uint4*)(wbf + (size_t)(co0 + row0) * KDIM + k0 + kc0);
        uint4 a1 = *(const uint4*)(head + (arow0 + row1) * KDIM + k0 + kc1);
        uint4 b1 = *(const uint4*)(wbf + (size_t)(co0 + row1) * KDIM + k0 + kc1);
        __syncthreads();
        *(uint4*)&Asl[tid * 8] = a0;
        *(uint4*)&Asl[(tid + 256) * 8] = a1;
        *(uint4*)&Bsl[tid * 8] = b0;
        *(uint4*)&Bsl[(tid + 256) * 8] = b1;
        __syncthreads();

        bf16x8 af[4], bf[4];
#pragma unroll
        for (int f = 0; f < 4; ++f) {
            af[f] = *(const bf16x8*)&Asl[(wm * 64 + f * 16 + l15) * 32 + g * 8];
            bf[f] = *(const bf16x8*)&Bsl[(wn * 64 + f * 16 + l15) * 32 + g * 8];
        }
#pragma unroll
        for (int i = 0; i < 4; ++i)
#pragma unroll
            for (int j = 0; j < 4; ++j)
                acc[i][j] = __builtin_amdgcn_mfma_f32_16x16x32_bf16(af[i], bf[j], acc[i][j], 0, 0, 0);
    }

    const int b = (int)(arow0 >> 12);
    const float al = alpha[b], il = 1.f - al;
    const int pixbase = (int)(arow0 & 4095);
#pragma unroll
    for (int i = 0; i < 4; ++i) {
        const int rowl = wm * 64 + i * 16 + g * 4;
        const int pix = pixbase + rowl;
#pragma unroll
        for (int j = 0; j < 4; ++j) {
            const int co = co0 + wn * 64 + j * 16 + l15;
            const float bias = bfuse[co];
            const size_t idx = (((size_t)b << 8) + co) * HWc + pix;
            const float4 fx = *(const float4*)(Fx + idx);
            const f32x4 v = acc[i][j];
            float4 o;
            o.x = al * (v[0] + bias) + il * fx.x;
            o.y = al * (v[1] + bias) + il * fx.y;
            o.z = al * (v[2] + bias) + il * fx.z;
            o.w = al * (v[3] + bias) + il * fx.w;
            *(float4*)(dout + idx) = o;
        }
    }
}

// ---------------- launcher ----------------
extern "C" void kernel_launch(void* const* d_in, const int* in_sizes, int n_in,
                              void* d_out, int out_size, void* d_ws, size_t ws_size,
                              hipStream_t stream) {
    const float* F_x    = (const float*)d_in[0];
    const float* F_c    = (const float*)d_in[1];
    const float* t      = (const float*)d_in[2];
    const float* w_off  = (const float*)d_in[3];
    const float* b_off  = (const float*)d_in[4];
    const float* w_attn = (const float*)d_in[5];
    const float* b_attn = (const float*)d_in[6];
    const float* Wp     = (const float*)d_in[7];
    const float* w_fuse = (const float*)d_in[8];
    const float* b_fuse = (const float*)d_in[9];
    const float* w1     = (const float*)d_in[10];
    const float* b1     = (const float*)d_in[11];
    const float* w2     = (const float*)d_in[12];
    const float* b2     = (const float*)d_in[13];
    float* out = (float*)d_out;

    char* ws = (char*)d_ws;
    u16*   Xt    = (u16*)(ws + XT_OFF);
    u16*   Xlo   = (u16*)(ws + HEAD_OFF);     // aliases head (conv finishes first)
    u16*   head  = (u16*)(ws + HEAD_OFF);
    u16*   wbf   = (u16*)(ws + WBF_OFF);
    float* attnb = (float*)(ws + ATTN_OFF);
    float* alphb = (float*)(ws + ALPHA_OFF);
    float* lossp = (float*)(ws + LOSSP_OFF);
    u16*   wconv = (u16*)(ws + WREP_OFF);
    float* zpage = (float*)(ws + ZPAGE_OFF);

    pack_x<<<dim3(16384), dim3(256), 0, stream>>>(F_x, F_c, Xt, Xlo);
    prep<<<dim3(265), dim3(256), 0, stream>>>(w_fuse, wbf, w_off, w_attn, wconv, zpage);
    conv_mfma<<<dim3(256), dim3(512), 0, stream>>>(Xt, Xlo, wconv, zpage, b_off, b_attn,
                                                   out, attnb, lossp);
    finalize_small<<<dim3(1), dim3(256), 0, stream>>>(lossp, t, w1, b1, w2, b2, out, alphb);
    sample_head<<<dim3(32768), dim3(256), 0, stream>>>(Xt, out, attnb, Wp, head);
    fuse_gemm<<<dim3(256, 2), dim3(256), 0, stream>>>(head, wbf, F_x, b_fuse, alphb, out);
}